// Round 1
// baseline (74.312 us; speedup 1.0000x reference)
//
#include <hip/hip_runtime.h>
#include <math.h>

#define NPTS 4096
#define NBATCH 8

// ws layout (float offsets):
//   [0, 32)            centroid: 4 floats per batch (x,y,z,pad)
//   [32, 800)          fused coeffs: A0,A1,A2,vd,vl,beff each [128]
//   [800, 800+32768)   local density per (b,n)
#define WS_CENT 0
#define WS_COEF 32
#define WS_DENS 800

__global__ void centroid_kernel(const float* __restrict__ pts, float* __restrict__ ws) {
    int b = blockIdx.x;
    const float* P = pts + (size_t)b * NPTS * 3;
    __shared__ float sx[256], sy[256], sz[256];
    float ax = 0.f, ay = 0.f, az = 0.f;
    for (int n = threadIdx.x; n < NPTS; n += 256) {
        ax += P[3 * n + 0];
        ay += P[3 * n + 1];
        az += P[3 * n + 2];
    }
    sx[threadIdx.x] = ax; sy[threadIdx.x] = ay; sz[threadIdx.x] = az;
    __syncthreads();
    for (int off = 128; off > 0; off >>= 1) {
        if (threadIdx.x < off) {
            sx[threadIdx.x] += sx[threadIdx.x + off];
            sy[threadIdx.x] += sy[threadIdx.x + off];
            sz[threadIdx.x] += sz[threadIdx.x + off];
        }
        __syncthreads();
    }
    if (threadIdx.x == 0) {
        const float inv = 1.0f / (float)NPTS;
        ws[WS_CENT + 4 * b + 0] = sx[0] * inv;
        ws[WS_CENT + 4 * b + 1] = sy[0] * inv;
        ws[WS_CENT + 4 * b + 2] = sz[0] * inv;
    }
}

// Fold the two-layer linear stack into: out = rx*A0 + ry*A1 + rz*A2 + cd*vd + ld*vl + beff
__global__ void coeff_kernel(const float* __restrict__ W_rel, const float* __restrict__ b_rel,
                             const float* __restrict__ W_dist, const float* __restrict__ b_dist,
                             const float* __restrict__ W_dens, const float* __restrict__ b_dens,
                             const float* __restrict__ W_out, const float* __restrict__ b_out,
                             float* __restrict__ ws) {
    int o = threadIdx.x;  // 0..127
    float a0 = 0.f, a1 = 0.f, a2 = 0.f, vd = 0.f, vl = 0.f, be = b_out[o];
    for (int j = 0; j < 42; ++j) {
        float w0 = W_out[j * 128 + o];          // rel rows
        float w1 = W_out[(42 + j) * 128 + o];   // dist rows
        float w2 = W_out[(84 + j) * 128 + o];   // dens rows
        a0 = fmaf(W_rel[j],       w0, a0);
        a1 = fmaf(W_rel[42 + j],  w0, a1);
        a2 = fmaf(W_rel[84 + j],  w0, a2);
        vd = fmaf(W_dist[j],      w1, vd);
        vl = fmaf(W_dens[j],      w2, vl);
        be = fmaf(b_rel[j], w0, be);
        be = fmaf(b_dist[j], w1, be);
        be = fmaf(b_dens[j], w2, be);
    }
    float* C = ws + WS_COEF;
    C[0 * 128 + o] = a0;
    C[1 * 128 + o] = a1;
    C[2 * 128 + o] = a2;
    C[3 * 128 + o] = vd;
    C[4 * 128 + o] = vl;
    C[5 * 128 + o] = be;
}

// Insert value v into sorted ascending triple (t0<=t1<=t2), keeping smallest 3.
#define INS3(v)                                          \
    {                                                    \
        bool c0 = (v) < t0, c1 = (v) < t1, c2 = (v) < t2;\
        float u2 = c1 ? t1 : (c2 ? (v) : t2);            \
        float u1 = c0 ? t0 : (c1 ? (v) : t1);            \
        float u0 = c0 ? (v) : t0;                        \
        t0 = u0; t1 = u1; t2 = u2;                       \
    }

// One block = 32 query points of one batch; 8 lanes per query each scan an
// interleaved 1/8 of the 4096 candidates from LDS, then shuffle-merge top-3.
__launch_bounds__(256)
__global__ void density_kernel(const float* __restrict__ pts, float* __restrict__ ws) {
    __shared__ float lp[NPTS * 3];  // 48 KB AoS
    int b = blockIdx.x >> 7;        // /128
    int chunk = blockIdx.x & 127;
    const float* P = pts + (size_t)b * NPTS * 3;
    for (int idx = threadIdx.x; idx < NPTS * 3; idx += 256) lp[idx] = P[idx];
    __syncthreads();

    int n = (chunk << 5) + (threadIdx.x >> 3);
    int s = threadIdx.x & 7;
    float xn = lp[3 * n + 0], yn = lp[3 * n + 1], zn = lp[3 * n + 2];
    float t0 = INFINITY, t1 = INFINITY, t2 = INFINITY;

    for (int i = 0; i < NPTS / 8; ++i) {
        int m = (i << 3) + s;              // m = 8i+s: 8 distinct banks, broadcast x8
        float dx = xn - lp[3 * m + 0];
        float dy = yn - lp[3 * m + 1];
        float dz = zn - lp[3 * m + 2];
        float d2 = fmaf(dx, dx, fmaf(dy, dy, dz * dz));
        d2 = (m == n) ? INFINITY : d2;     // exclude self
        INS3(d2);
    }
    // merge the 8 partial top-3 sets within each 8-lane group
    for (int off = 1; off < 8; off <<= 1) {
        float o0 = __shfl_xor(t0, off);
        float o1 = __shfl_xor(t1, off);
        float o2 = __shfl_xor(t2, off);
        INS3(o0);
        INS3(o1);
        INS3(o2);
    }
    if (s == 0) {
        float d = (sqrtf(fmaxf(t0, 1e-12f)) +
                   sqrtf(fmaxf(t1, 1e-12f)) +
                   sqrtf(fmaxf(t2, 1e-12f))) * (1.0f / 3.0f);
        ws[WS_DENS + b * NPTS + n] = d;
    }
}

// 256 threads = 8 points x 32 quads; each thread writes one float4 of the 128-wide output.
__launch_bounds__(256)
__global__ void output_kernel(const float* __restrict__ pts, const float* __restrict__ ws,
                              float* __restrict__ out) {
    int blk = blockIdx.x;
    int b = blk >> 9;                 // /512
    int pg = blk & 511;
    int n = (pg << 3) + (threadIdx.x >> 5);
    int q = threadIdx.x & 31;
    int o = q * 4;

    const float* C = ws + WS_COEF;
    float cx = ws[WS_CENT + 4 * b + 0];
    float cy = ws[WS_CENT + 4 * b + 1];
    float cz = ws[WS_CENT + 4 * b + 2];
    const float* P = pts + ((size_t)b * NPTS + n) * 3;
    float rx = P[0] - cx, ry = P[1] - cy, rz = P[2] - cz;
    float cd = sqrtf(fmaf(rx, rx, fmaf(ry, ry, rz * rz)));
    float ld = ws[WS_DENS + b * NPTS + n];

    float4 A0 = *(const float4*)(C + 0 * 128 + o);
    float4 A1 = *(const float4*)(C + 1 * 128 + o);
    float4 A2 = *(const float4*)(C + 2 * 128 + o);
    float4 VD = *(const float4*)(C + 3 * 128 + o);
    float4 VL = *(const float4*)(C + 4 * 128 + o);
    float4 BE = *(const float4*)(C + 5 * 128 + o);

    float4 r;
    r.x = fmaf(rx, A0.x, fmaf(ry, A1.x, fmaf(rz, A2.x, fmaf(cd, VD.x, fmaf(ld, VL.x, BE.x)))));
    r.y = fmaf(rx, A0.y, fmaf(ry, A1.y, fmaf(rz, A2.y, fmaf(cd, VD.y, fmaf(ld, VL.y, BE.y)))));
    r.z = fmaf(rx, A0.z, fmaf(ry, A1.z, fmaf(rz, A2.z, fmaf(cd, VD.z, fmaf(ld, VL.z, BE.z)))));
    r.w = fmaf(rx, A0.w, fmaf(ry, A1.w, fmaf(rz, A2.w, fmaf(cd, VD.w, fmaf(ld, VL.w, BE.w)))));

    *(float4*)(out + ((size_t)(b * NPTS + n)) * 128 + o) = r;
}

extern "C" void kernel_launch(void* const* d_in, const int* in_sizes, int n_in,
                              void* d_out, int out_size, void* d_ws, size_t ws_size,
                              hipStream_t stream) {
    const float* pts    = (const float*)d_in[0];
    const float* W_rel  = (const float*)d_in[1];
    const float* b_rel  = (const float*)d_in[2];
    const float* W_dist = (const float*)d_in[3];
    const float* b_dist = (const float*)d_in[4];
    const float* W_dens = (const float*)d_in[5];
    const float* b_dens = (const float*)d_in[6];
    const float* W_out  = (const float*)d_in[7];
    const float* b_out  = (const float*)d_in[8];
    float* out = (float*)d_out;
    float* ws  = (float*)d_ws;

    hipLaunchKernelGGL(centroid_kernel, dim3(NBATCH), dim3(256), 0, stream, pts, ws);
    hipLaunchKernelGGL(coeff_kernel, dim3(1), dim3(128), 0, stream,
                       W_rel, b_rel, W_dist, b_dist, W_dens, b_dens, W_out, b_out, ws);
    hipLaunchKernelGGL(density_kernel, dim3(NBATCH * 128), dim3(256), 0, stream, pts, ws);
    hipLaunchKernelGGL(output_kernel, dim3(NBATCH * 512), dim3(256), 0, stream, pts, ws, out);
}

// Round 2
// 54.405 us; speedup vs baseline: 1.3659x; 1.3659x over previous
//
#include <hip/hip_runtime.h>
#include <math.h>

#define NPTS 4096
#define NBATCH 8

// ws layout (float offsets):
//   [0, 32)            centroid: 4 floats per batch (x,y,z,pad)
//   [32, 800)          fused coeffs: A0,A1,A2,vd,vl,beff each [128]
//   [800, 800+32768)   local density per (b,n)
#define WS_CENT 0
#define WS_COEF 32
#define WS_DENS 800

__global__ void centroid_kernel(const float* __restrict__ pts, float* __restrict__ ws) {
    int b = blockIdx.x;
    const float* P = pts + (size_t)b * NPTS * 3;
    __shared__ float sx[256], sy[256], sz[256];
    float ax = 0.f, ay = 0.f, az = 0.f;
    for (int n = threadIdx.x; n < NPTS; n += 256) {
        ax += P[3 * n + 0];
        ay += P[3 * n + 1];
        az += P[3 * n + 2];
    }
    sx[threadIdx.x] = ax; sy[threadIdx.x] = ay; sz[threadIdx.x] = az;
    __syncthreads();
    for (int off = 128; off > 0; off >>= 1) {
        if (threadIdx.x < off) {
            sx[threadIdx.x] += sx[threadIdx.x + off];
            sy[threadIdx.x] += sy[threadIdx.x + off];
            sz[threadIdx.x] += sz[threadIdx.x + off];
        }
        __syncthreads();
    }
    if (threadIdx.x == 0) {
        const float inv = 1.0f / (float)NPTS;
        ws[WS_CENT + 4 * b + 0] = sx[0] * inv;
        ws[WS_CENT + 4 * b + 1] = sy[0] * inv;
        ws[WS_CENT + 4 * b + 2] = sz[0] * inv;
    }
}

// Fold the two-layer linear stack into: out = rx*A0 + ry*A1 + rz*A2 + cd*vd + ld*vl + beff
__global__ void coeff_kernel(const float* __restrict__ W_rel, const float* __restrict__ b_rel,
                             const float* __restrict__ W_dist, const float* __restrict__ b_dist,
                             const float* __restrict__ W_dens, const float* __restrict__ b_dens,
                             const float* __restrict__ W_out, const float* __restrict__ b_out,
                             float* __restrict__ ws) {
    int o = threadIdx.x;  // 0..127
    float a0 = 0.f, a1 = 0.f, a2 = 0.f, vd = 0.f, vl = 0.f, be = b_out[o];
    for (int j = 0; j < 42; ++j) {
        float w0 = W_out[j * 128 + o];          // rel rows
        float w1 = W_out[(42 + j) * 128 + o];   // dist rows
        float w2 = W_out[(84 + j) * 128 + o];   // dens rows
        a0 = fmaf(W_rel[j],       w0, a0);
        a1 = fmaf(W_rel[42 + j],  w0, a1);
        a2 = fmaf(W_rel[84 + j],  w0, a2);
        vd = fmaf(W_dist[j],      w1, vd);
        vl = fmaf(W_dens[j],      w2, vl);
        be = fmaf(b_rel[j], w0, be);
        be = fmaf(b_dist[j], w1, be);
        be = fmaf(b_dens[j], w2, be);
    }
    float* C = ws + WS_COEF;
    C[0 * 128 + o] = a0;
    C[1 * 128 + o] = a1;
    C[2 * 128 + o] = a2;
    C[3 * 128 + o] = vd;
    C[4 * 128 + o] = vl;
    C[5 * 128 + o] = be;
}

// 5-op sorted-triple insert (t0<=t1<=t2 invariant), min/max network.
#define INS3MM(v)                              \
    {                                          \
        float u0 = fminf(t0, (v));             \
        float ca = fmaxf(t0, (v));             \
        float u1 = fminf(t1, ca);              \
        float cb = fmaxf(t1, ca);              \
        float u2 = fminf(t2, cb);              \
        t0 = u0; t1 = u1; t2 = u2;             \
    }

// Block = 512 threads = 64 queries x 8 candidate-slices. Candidates staged in
// LDS as float4 (x,y,z,|p|^2). Each wave's 64 lanes hold 64 distinct queries
// and broadcast-read the SAME candidate each iteration (uniform LDS address).
// Track e = sq_m - 2*dot(n,m) (order-equivalent to d^2 shifted by sq_n).
__launch_bounds__(512)
__global__ void density_kernel(const float* __restrict__ pts, float* __restrict__ ws) {
    __shared__ float4 lp4[NPTS];       // 64 KB
    __shared__ float mrg[8][64][4];    // 8 KB partial top-3 per (slice, query)
    int b = blockIdx.x >> 6;           // 8 batches
    int g = blockIdx.x & 63;           // 64 query-groups of 64
    const float* P = pts + (size_t)b * NPTS * 3;
    for (int k = threadIdx.x; k < NPTS; k += 512) {
        float x = P[3 * k + 0], y = P[3 * k + 1], z = P[3 * k + 2];
        lp4[k] = make_float4(x, y, z, fmaf(x, x, fmaf(y, y, z * z)));
    }
    __syncthreads();

    int s = threadIdx.x >> 6;          // slice 0..7
    int q = threadIdx.x & 63;          // query lane 0..63
    int nloc = (g << 6) + q;           // query index within batch
    float4 me = lp4[nloc];
    float xn2 = -2.0f * me.x, yn2 = -2.0f * me.y, zn2 = -2.0f * me.z;
    float sqn = me.w;
    float t0 = INFINITY, t1 = INFINITY, t2 = INFINITY;

    int base = s << 9;                 // s*512
    #pragma unroll 8
    for (int i = 0; i < 512; ++i) {
        int idx = base + i;
        float4 c = lp4[idx];           // wave-uniform address: LDS broadcast
        float e = fmaf(xn2, c.x, fmaf(yn2, c.y, fmaf(zn2, c.z, c.w)));
        e = (idx == nloc) ? INFINITY : e;   // exclude self
        INS3MM(e);
    }
    mrg[s][q][0] = t0; mrg[s][q][1] = t1; mrg[s][q][2] = t2;
    __syncthreads();

    if (threadIdx.x < 64) {            // wave 0, s==0: own partial already in regs
        for (int sl = 1; sl < 8; ++sl) {
            float e0 = mrg[sl][q][0], e1 = mrg[sl][q][1], e2 = mrg[sl][q][2];
            INS3MM(e0);
            INS3MM(e1);
            INS3MM(e2);
        }
        float d = (sqrtf(fmaxf(t0 + sqn, 1e-12f)) +
                   sqrtf(fmaxf(t1 + sqn, 1e-12f)) +
                   sqrtf(fmaxf(t2 + sqn, 1e-12f))) * (1.0f / 3.0f);
        ws[WS_DENS + b * NPTS + nloc] = d;
    }
}

// 256 threads = 8 points x 32 quads; each thread writes one float4 of the 128-wide output.
__launch_bounds__(256)
__global__ void output_kernel(const float* __restrict__ pts, const float* __restrict__ ws,
                              float* __restrict__ out) {
    int blk = blockIdx.x;
    int b = blk >> 9;                 // /512
    int pg = blk & 511;
    int n = (pg << 3) + (threadIdx.x >> 5);
    int q = threadIdx.x & 31;
    int o = q * 4;

    const float* C = ws + WS_COEF;
    float cx = ws[WS_CENT + 4 * b + 0];
    float cy = ws[WS_CENT + 4 * b + 1];
    float cz = ws[WS_CENT + 4 * b + 2];
    const float* P = pts + ((size_t)b * NPTS + n) * 3;
    float rx = P[0] - cx, ry = P[1] - cy, rz = P[2] - cz;
    float cd = sqrtf(fmaf(rx, rx, fmaf(ry, ry, rz * rz)));
    float ld = ws[WS_DENS + b * NPTS + n];

    float4 A0 = *(const float4*)(C + 0 * 128 + o);
    float4 A1 = *(const float4*)(C + 1 * 128 + o);
    float4 A2 = *(const float4*)(C + 2 * 128 + o);
    float4 VD = *(const float4*)(C + 3 * 128 + o);
    float4 VL = *(const float4*)(C + 4 * 128 + o);
    float4 BE = *(const float4*)(C + 5 * 128 + o);

    float4 r;
    r.x = fmaf(rx, A0.x, fmaf(ry, A1.x, fmaf(rz, A2.x, fmaf(cd, VD.x, fmaf(ld, VL.x, BE.x)))));
    r.y = fmaf(rx, A0.y, fmaf(ry, A1.y, fmaf(rz, A2.y, fmaf(cd, VD.y, fmaf(ld, VL.y, BE.y)))));
    r.z = fmaf(rx, A0.z, fmaf(ry, A1.z, fmaf(rz, A2.z, fmaf(cd, VD.z, fmaf(ld, VL.z, BE.z)))));
    r.w = fmaf(rx, A0.w, fmaf(ry, A1.w, fmaf(rz, A2.w, fmaf(cd, VD.w, fmaf(ld, VL.w, BE.w)))));

    *(float4*)(out + ((size_t)(b * NPTS + n)) * 128 + o) = r;
}

extern "C" void kernel_launch(void* const* d_in, const int* in_sizes, int n_in,
                              void* d_out, int out_size, void* d_ws, size_t ws_size,
                              hipStream_t stream) {
    const float* pts    = (const float*)d_in[0];
    const float* W_rel  = (const float*)d_in[1];
    const float* b_rel  = (const float*)d_in[2];
    const float* W_dist = (const float*)d_in[3];
    const float* b_dist = (const float*)d_in[4];
    const float* W_dens = (const float*)d_in[5];
    const float* b_dens = (const float*)d_in[6];
    const float* W_out  = (const float*)d_in[7];
    const float* b_out  = (const float*)d_in[8];
    float* out = (float*)d_out;
    float* ws  = (float*)d_ws;

    hipLaunchKernelGGL(centroid_kernel, dim3(NBATCH), dim3(256), 0, stream, pts, ws);
    hipLaunchKernelGGL(coeff_kernel, dim3(1), dim3(128), 0, stream,
                       W_rel, b_rel, W_dist, b_dist, W_dens, b_dens, W_out, b_out, ws);
    hipLaunchKernelGGL(density_kernel, dim3(NBATCH * 64), dim3(512), 0, stream, pts, ws);
    hipLaunchKernelGGL(output_kernel, dim3(NBATCH * 512), dim3(256), 0, stream, pts, ws, out);
}

// Round 3
// 38.950 us; speedup vs baseline: 1.9079x; 1.3968x over previous
//
#include <hip/hip_runtime.h>
#include <math.h>

#define NPTS 4096
#define NBATCH 8

// ws layout (float offsets):
//   [0, 32)    centroid: 4 floats per batch (x,y,z,pad)
//   [32, 800)  fused coeffs: A0,A1,A2,vd,vl,beff each [128]
#define WS_CENT 0
#define WS_COEF 32

// blocks 0..7: centroid per batch; block 8: coeff fold.
__global__ void prep_kernel(const float* __restrict__ pts,
                            const float* __restrict__ W_rel, const float* __restrict__ b_rel,
                            const float* __restrict__ W_dist, const float* __restrict__ b_dist,
                            const float* __restrict__ W_dens, const float* __restrict__ b_dens,
                            const float* __restrict__ W_out, const float* __restrict__ b_out,
                            float* __restrict__ ws) {
    __shared__ float sx[256], sy[256], sz[256];
    if (blockIdx.x < NBATCH) {
        int b = blockIdx.x;
        const float* P = pts + (size_t)b * NPTS * 3;
        float ax = 0.f, ay = 0.f, az = 0.f;
        for (int n = threadIdx.x; n < NPTS; n += 256) {
            ax += P[3 * n + 0];
            ay += P[3 * n + 1];
            az += P[3 * n + 2];
        }
        sx[threadIdx.x] = ax; sy[threadIdx.x] = ay; sz[threadIdx.x] = az;
        __syncthreads();
        for (int off = 128; off > 0; off >>= 1) {
            if (threadIdx.x < off) {
                sx[threadIdx.x] += sx[threadIdx.x + off];
                sy[threadIdx.x] += sy[threadIdx.x + off];
                sz[threadIdx.x] += sz[threadIdx.x + off];
            }
            __syncthreads();
        }
        if (threadIdx.x == 0) {
            const float inv = 1.0f / (float)NPTS;
            ws[WS_CENT + 4 * b + 0] = sx[0] * inv;
            ws[WS_CENT + 4 * b + 1] = sy[0] * inv;
            ws[WS_CENT + 4 * b + 2] = sz[0] * inv;
        }
    } else if (threadIdx.x < 128) {
        int o = threadIdx.x;
        float a0 = 0.f, a1 = 0.f, a2 = 0.f, vd = 0.f, vl = 0.f, be = b_out[o];
        for (int j = 0; j < 42; ++j) {
            float w0 = W_out[j * 128 + o];
            float w1 = W_out[(42 + j) * 128 + o];
            float w2 = W_out[(84 + j) * 128 + o];
            a0 = fmaf(W_rel[j],      w0, a0);
            a1 = fmaf(W_rel[42 + j], w0, a1);
            a2 = fmaf(W_rel[84 + j], w0, a2);
            vd = fmaf(W_dist[j],     w1, vd);
            vl = fmaf(W_dens[j],     w2, vl);
            be = fmaf(b_rel[j], w0, be);
            be = fmaf(b_dist[j], w1, be);
            be = fmaf(b_dens[j], w2, be);
        }
        float* C = ws + WS_COEF;
        C[0 * 128 + o] = a0;
        C[1 * 128 + o] = a1;
        C[2 * 128 + o] = a2;
        C[3 * 128 + o] = vd;
        C[4 * 128 + o] = vl;
        C[5 * 128 + o] = be;
    }
}

// 3-op sorted-triple insert via med3 (rank-k insert identity).
#define INS3(t0, t1, t2, v)                                   \
    {                                                         \
        float n0 = fminf(t0, (v));                            \
        float n1 = __builtin_amdgcn_fmed3f(t0, t1, (v));      \
        float n2 = __builtin_amdgcn_fmed3f(t1, t2, (v));      \
        t0 = n0; t1 = n1; t2 = n2;                            \
    }

// Merge partner's sorted triple (7 min/max) via xor-butterfly step.
#define MERGE3(t0, t1, t2, m)                                 \
    {                                                         \
        float b0 = __shfl_xor(t0, m);                         \
        float b1 = __shfl_xor(t1, m);                         \
        float b2 = __shfl_xor(t2, m);                         \
        float X = fmaxf(t0, b0);                              \
        t0 = fminf(t0, b0);                                   \
        float Y = fminf(t1, b1);                              \
        float Z = fmaxf(X, Y);                                \
        t1 = fminf(X, Y);                                     \
        t2 = fminf(Z, fminf(t2, b2));                         \
    }

// Block = 1024 threads = 16 waves, 64 queries of one batch (4 per wave).
// Lane holds a candidate (x,y,z,|p|^2) from LDS: 1 ds_read_b128 serves 64
// candidates. e = sq_m - 2*dot (order-equiv to d^2). Self excluded post-hoc:
// its e is the strict lane-minimum, so the owning lane shifts its triple.
// Epilogue: fused 64x128 output tile (GEMV on folded coeffs).
__launch_bounds__(1024, 8)
__global__ void density_out_kernel(const float* __restrict__ pts,
                                   const float* __restrict__ ws,
                                   float* __restrict__ out) {
    __shared__ float4 lp4[NPTS];   // 64 KB
    __shared__ float dens[64];
    int b = blockIdx.x >> 6;
    int g = blockIdx.x & 63;
    int tid = threadIdx.x;

    // stage: thread t -> points 4t..4t+3 (3 coalesced float4 loads)
    {
        const float4* P4 = (const float4*)(pts + (size_t)b * NPTS * 3);
        float4 v0 = P4[3 * tid + 0];
        float4 v1 = P4[3 * tid + 1];
        float4 v2 = P4[3 * tid + 2];
        float x0 = v0.x, y0 = v0.y, z0 = v0.z;
        float x1 = v0.w, y1 = v1.x, z1 = v1.y;
        float x2 = v1.z, y2 = v1.w, z2 = v2.x;
        float x3 = v2.y, y3 = v2.z, z3 = v2.w;
        lp4[4 * tid + 0] = make_float4(x0, y0, z0, fmaf(x0, x0, fmaf(y0, y0, z0 * z0)));
        lp4[4 * tid + 1] = make_float4(x1, y1, z1, fmaf(x1, x1, fmaf(y1, y1, z1 * z1)));
        lp4[4 * tid + 2] = make_float4(x2, y2, z2, fmaf(x2, x2, fmaf(y2, y2, z2 * z2)));
        lp4[4 * tid + 3] = make_float4(x3, y3, z3, fmaf(x3, x3, fmaf(y3, y3, z3 * z3)));
    }
    __syncthreads();

    int w = tid >> 6;
    int lane = tid & 63;
    int lw = w << 2;                 // local query base (0..60)
    int qb = (g << 6) + lw;          // within-batch query base

    float4 Q0 = lp4[qb + 0];
    float4 Q1 = lp4[qb + 1];
    float4 Q2 = lp4[qb + 2];
    float4 Q3 = lp4[qb + 3];
    float q0x = -2.f * Q0.x, q0y = -2.f * Q0.y, q0z = -2.f * Q0.z;
    float q1x = -2.f * Q1.x, q1y = -2.f * Q1.y, q1z = -2.f * Q1.z;
    float q2x = -2.f * Q2.x, q2y = -2.f * Q2.y, q2z = -2.f * Q2.z;
    float q3x = -2.f * Q3.x, q3y = -2.f * Q3.y, q3z = -2.f * Q3.z;

    float t00 = INFINITY, t01 = INFINITY, t02 = INFINITY;
    float t10 = INFINITY, t11 = INFINITY, t12 = INFINITY;
    float t20 = INFINITY, t21 = INFINITY, t22 = INFINITY;
    float t30 = INFINITY, t31 = INFINITY, t32 = INFINITY;

    #pragma unroll 4
    for (int tile = 0; tile < 64; ++tile) {
        float4 c = lp4[(tile << 6) + lane];
        float e0 = fmaf(q0x, c.x, fmaf(q0y, c.y, fmaf(q0z, c.z, c.w)));
        float e1 = fmaf(q1x, c.x, fmaf(q1y, c.y, fmaf(q1z, c.z, c.w)));
        float e2 = fmaf(q2x, c.x, fmaf(q2y, c.y, fmaf(q2z, c.z, c.w)));
        float e3 = fmaf(q3x, c.x, fmaf(q3y, c.y, fmaf(q3z, c.z, c.w)));
        INS3(t00, t01, t02, e0);
        INS3(t10, t11, t12, e1);
        INS3(t20, t21, t22, e2);
        INS3(t30, t31, t32, e3);
    }

    // self removal: query j's self sits on lane lw+j and is that lane's t0
    if (lane == lw + 0) { t00 = t01; t01 = t02; t02 = INFINITY; }
    if (lane == lw + 1) { t10 = t11; t11 = t12; t12 = INFINITY; }
    if (lane == lw + 2) { t20 = t21; t21 = t22; t22 = INFINITY; }
    if (lane == lw + 3) { t30 = t31; t31 = t32; t32 = INFINITY; }

    #pragma unroll
    for (int m = 1; m < 64; m <<= 1) {
        MERGE3(t00, t01, t02, m);
        MERGE3(t10, t11, t12, m);
        MERGE3(t20, t21, t22, m);
        MERGE3(t30, t31, t32, m);
    }

    if (lane == 0) {
        dens[lw + 0] = (sqrtf(fmaxf(t00 + Q0.w, 1e-12f)) + sqrtf(fmaxf(t01 + Q0.w, 1e-12f)) +
                        sqrtf(fmaxf(t02 + Q0.w, 1e-12f))) * (1.0f / 3.0f);
        dens[lw + 1] = (sqrtf(fmaxf(t10 + Q1.w, 1e-12f)) + sqrtf(fmaxf(t11 + Q1.w, 1e-12f)) +
                        sqrtf(fmaxf(t12 + Q1.w, 1e-12f))) * (1.0f / 3.0f);
        dens[lw + 2] = (sqrtf(fmaxf(t20 + Q2.w, 1e-12f)) + sqrtf(fmaxf(t21 + Q2.w, 1e-12f)) +
                        sqrtf(fmaxf(t22 + Q2.w, 1e-12f))) * (1.0f / 3.0f);
        dens[lw + 3] = (sqrtf(fmaxf(t30 + Q3.w, 1e-12f)) + sqrtf(fmaxf(t31 + Q3.w, 1e-12f)) +
                        sqrtf(fmaxf(t32 + Q3.w, 1e-12f))) * (1.0f / 3.0f);
    }
    __syncthreads();

    // epilogue: 64 rows x 128 cols; thread -> (row, 8 cols) in two float4 halves
    int r = tid >> 4;
    int c8 = (tid & 15) << 3;
    float4 p = lp4[(g << 6) + r];
    float cx = ws[WS_CENT + 4 * b + 0];
    float cy = ws[WS_CENT + 4 * b + 1];
    float cz = ws[WS_CENT + 4 * b + 2];
    float rx = p.x - cx, ry = p.y - cy, rz = p.z - cz;
    float cd = sqrtf(fmaf(rx, rx, fmaf(ry, ry, rz * rz)));
    float ld = dens[r];
    const float* C = ws + WS_COEF;
    float* orow = out + ((size_t)(b * NPTS + (g << 6) + r)) * 128;
    #pragma unroll
    for (int h = 0; h < 2; ++h) {
        int o = c8 + 4 * h;
        float4 A0 = *(const float4*)(C + 0 * 128 + o);
        float4 A1 = *(const float4*)(C + 1 * 128 + o);
        float4 A2 = *(const float4*)(C + 2 * 128 + o);
        float4 VD = *(const float4*)(C + 3 * 128 + o);
        float4 VL = *(const float4*)(C + 4 * 128 + o);
        float4 BE = *(const float4*)(C + 5 * 128 + o);
        float4 rv;
        rv.x = fmaf(rx, A0.x, fmaf(ry, A1.x, fmaf(rz, A2.x, fmaf(cd, VD.x, fmaf(ld, VL.x, BE.x)))));
        rv.y = fmaf(rx, A0.y, fmaf(ry, A1.y, fmaf(rz, A2.y, fmaf(cd, VD.y, fmaf(ld, VL.y, BE.y)))));
        rv.z = fmaf(rx, A0.z, fmaf(ry, A1.z, fmaf(rz, A2.z, fmaf(cd, VD.z, fmaf(ld, VL.z, BE.z)))));
        rv.w = fmaf(rx, A0.w, fmaf(ry, A1.w, fmaf(rz, A2.w, fmaf(cd, VD.w, fmaf(ld, VL.w, BE.w)))));
        *(float4*)(orow + o) = rv;
    }
}

extern "C" void kernel_launch(void* const* d_in, const int* in_sizes, int n_in,
                              void* d_out, int out_size, void* d_ws, size_t ws_size,
                              hipStream_t stream) {
    const float* pts    = (const float*)d_in[0];
    const float* W_rel  = (const float*)d_in[1];
    const float* b_rel  = (const float*)d_in[2];
    const float* W_dist = (const float*)d_in[3];
    const float* b_dist = (const float*)d_in[4];
    const float* W_dens = (const float*)d_in[5];
    const float* b_dens = (const float*)d_in[6];
    const float* W_out  = (const float*)d_in[7];
    const float* b_out  = (const float*)d_in[8];
    float* out = (float*)d_out;
    float* ws  = (float*)d_ws;

    hipLaunchKernelGGL(prep_kernel, dim3(NBATCH + 1), dim3(256), 0, stream,
                       pts, W_rel, b_rel, W_dist, b_dist, W_dens, b_dens, W_out, b_out, ws);
    hipLaunchKernelGGL(density_out_kernel, dim3(NBATCH * 64), dim3(1024), 0, stream,
                       pts, ws, out);
}